// Round 3
// baseline (388.248 us; speedup 1.0000x reference)
//
#include <hip/hip_runtime.h>

#define NPART 1000000
#define NGRID 128
#define NNODES (NGRID * NGRID)
#define NBINS 64               // 8x8 tiles of 16x16 nodes
#define SUBW 18                // 16 + 2 halo (high side)
#define SUBN (SUBW * SUBW)     // 324
#define P2G_SUB 8              // sub-blocks per tile
#define P2G_THREADS 512
#define PS_CHUNK 4
#define PS_BLOCKS 977          // ceil(1e6 / (256*4))
#define HIST_BLOCKS 489        // ceil(1e6 / (256*8))

// Output flat offsets (floats), return order: x, v, C, F, material, Jp
#define OUT_X   0
#define OUT_V   2000000
#define OUT_C   4000000
#define OUT_F   8000000
#define OUT_MAT 12000000
#define OUT_JP  13000000

__device__ __forceinline__ void quad_weights(float fx, float w[3]) {
    w[0] = 0.5f * (1.5f - fx) * (1.5f - fx);
    w[1] = 0.75f - (fx - 1.0f) * (fx - 1.0f);
    w[2] = 0.5f * (fx - 0.5f) * (fx - 0.5f);
}

struct PhysOut {
    float o00, o01, o10, o11;      // projected F (output)
    float aff00, aff01, aff10, aff11;
    float mom0, mom1;
    float jp_new;
};

__device__ __forceinline__ PhysOut particle_phys(
    float2 xx, float2 vv, float4 Cm, float4 Fin, int mat, float jp)
{
    const float DT = 1e-4f;
    const float P_MASS = 1.52587890625e-05f;
    const float MU_0 = (float)(1000.0 / (2.0 * 1.2));
    const float LAMBDA_0 = (float)(200.0 / 0.72);
    const float SCALE = -1e-4f;   // -DT*P_VOL*4*INV_DX^2 == -DT exactly

    float F00 = Fin.x + DT * (Cm.x * Fin.x + Cm.y * Fin.z);
    float F01 = Fin.y + DT * (Cm.x * Fin.y + Cm.y * Fin.w);
    float F10 = Fin.z + DT * (Cm.z * Fin.x + Cm.w * Fin.z);
    float F11 = Fin.w + DT * (Cm.z * Fin.y + Cm.w * Fin.w);

    float h = (mat == 1) ? 0.3f : expf(10.0f * (1.0f - jp));
    float mu = (mat == 0) ? 0.0f : MU_0 * h;
    float lam = LAMBDA_0 * h;

    // closed-form 2x2 SVD
    float Es = 0.5f * (F00 + F11), Fs = 0.5f * (F00 - F11);
    float Gs = 0.5f * (F01 + F10), Hs = 0.5f * (F10 - F01);
    float Qs = sqrtf(Es * Es + Hs * Hs);
    float Rs = sqrtf(Fs * Fs + Gs * Gs);
    float s1 = Qs + Rs, s2 = Qs - Rs;
    float a_sum = atan2f(Gs, Fs);
    float a_dif = atan2f(Hs, Es);
    float ua = 0.5f * (a_sum + a_dif);
    float va = 0.5f * (a_sum - a_dif);
    float su, cu, sv, cv;
    sincosf(ua, &su, &cu);
    sincosf(va, &sv, &cv);

    float c1 = fminf(fmaxf(s1, 1.0f - 2.5e-2f), 1.0f + 4.5e-3f);
    float c2 = fminf(fmaxf(s2, 1.0f - 2.5e-2f), 1.0f + 4.5e-3f);
    float jp_new = jp;
    float sg1 = s1, sg2 = s2;
    if (mat == 2) {
        jp_new = jp * (s1 / c1) * (s2 / c2);
        sg1 = c1;
        sg2 = c2;
    }
    float J = sg1 * sg2;

    float R00 = cu * cv + su * sv;
    float R01 = cu * sv - su * cv;
    float R10 = su * cv - cu * sv;
    float R11 = su * sv + cu * cv;

    float o00, o01, o10, o11;
    if (mat == 0) {
        float sq = sqrtf(J);
        o00 = sq; o01 = 0.0f; o10 = 0.0f; o11 = sq;
    } else if (mat == 2) {
        o00 = sg1 * cu * cv + sg2 * su * sv;
        o01 = sg1 * cu * sv - sg2 * su * cv;
        o10 = sg1 * su * cv - sg2 * cu * sv;
        o11 = sg1 * su * sv + sg2 * cu * cv;
    } else {
        o00 = F00; o01 = F01; o10 = F10; o11 = F11;
    }

    float A00 = o00 - R00, A01 = o01 - R01, A10 = o10 - R10, A11 = o11 - R11;
    float S00 = A00 * o00 + A01 * o01;
    float S01 = A00 * o10 + A01 * o11;
    float S10 = A10 * o00 + A11 * o01;
    float S11 = A10 * o10 + A11 * o11;
    float ljj = lam * J * (J - 1.0f);

    PhysOut po;
    po.o00 = o00; po.o01 = o01; po.o10 = o10; po.o11 = o11;
    po.aff00 = SCALE * (2.0f * mu * S00 + ljj) + P_MASS * Cm.x;
    po.aff01 = SCALE * (2.0f * mu * S01)       + P_MASS * Cm.y;
    po.aff10 = SCALE * (2.0f * mu * S10)       + P_MASS * Cm.z;
    po.aff11 = SCALE * (2.0f * mu * S11 + ljj) + P_MASS * Cm.w;
    po.mom0 = P_MASS * vv.x - (po.aff00 * xx.x + po.aff01 * xx.y);
    po.mom1 = P_MASS * vv.y - (po.aff10 * xx.x + po.aff11 * xx.y);
    po.jp_new = jp_new;
    return po;
}

__device__ __forceinline__ int tile_of(float2 xx) {
    int b0 = (int)floorf(xx.x * 128.0f - 0.5f);
    int b1 = (int)floorf(xx.y * 128.0f - 0.5f);
    return ((b0 >> 4) << 3) | (b1 >> 4);
}

// ---- Pass 1: bin counts (LDS-reduced, 8 particles/thread) ----
__global__ __launch_bounds__(256) void hist_kernel(
    const float2* __restrict__ x, int* __restrict__ binCount)
{
    __shared__ int lh[NBINS];
    int tid = threadIdx.x;
    if (tid < NBINS) lh[tid] = 0;
    __syncthreads();
    int base = blockIdx.x * 2048;
    #pragma unroll
    for (int k = 0; k < 8; ++k) {
        int n = base + k * 256 + tid;
        if (n < NPART) atomicAdd(&lh[tile_of(x[n])], 1);
    }
    __syncthreads();
    if (tid < NBINS) {
        int c = lh[tid];
        if (c) atomicAdd(&binCount[tid], c);
    }
}

// ---- Pass 2: exclusive scan of 64 bin totals (one wave) ----
__global__ void base_kernel(const int* __restrict__ binCount,
                            int* __restrict__ binBase, int* __restrict__ binCursor)
{
    int lane = threadIdx.x;   // 64 threads
    int v = binCount[lane];
    int incl = v;
    for (int off = 1; off < 64; off <<= 1) {
        int t = __shfl_up(incl, off, 64);
        if (lane >= off) incl += t;
    }
    binBase[lane] = incl - v;
    binCursor[lane] = incl - v;
}

// ---- Pass 3: physics + packed-record scatter + F/mat/Jp outputs ----
__global__ __launch_bounds__(256) void phys_scatter_kernel(
    const float2* __restrict__ x, const float2* __restrict__ v,
    const float4* __restrict__ C, const float4* __restrict__ F,
    const int* __restrict__ material, const float* __restrict__ Jp,
    int* __restrict__ binCursor, float* __restrict__ out, float4* __restrict__ rec)
{
    __shared__ int lh[NBINS];
    __shared__ int lbase[NBINS];
    int tid = threadIdx.x;
    if (tid < NBINS) lh[tid] = 0;
    __syncthreads();
    int base = blockIdx.x * (256 * PS_CHUNK);

    float2 xs[PS_CHUNK], vs[PS_CHUNK];
    float4 Cs[PS_CHUNK], Fs[PS_CHUNK];
    float jps[PS_CHUNK];
    int ms[PS_CHUNK], pk[PS_CHUNK];

    #pragma unroll
    for (int c = 0; c < PS_CHUNK; ++c) {
        int n = base + c * 256 + tid;
        if (n < NPART) {
            xs[c] = x[n]; vs[c] = v[n]; Cs[c] = C[n]; Fs[c] = F[n];
            ms[c] = material[n]; jps[c] = Jp[n];
            int t = tile_of(xs[c]);
            int r = atomicAdd(&lh[t], 1);
            pk[c] = (t << 16) | r;
        } else pk[c] = -1;
    }
    __syncthreads();
    if (tid < NBINS) {
        int c = lh[tid];
        lbase[tid] = c ? atomicAdd(&binCursor[tid], c) : 0;
    }
    __syncthreads();

    #pragma unroll
    for (int c = 0; c < PS_CHUNK; ++c) {
        if (pk[c] < 0) continue;
        int n = base + c * 256 + tid;
        PhysOut po = particle_phys(xs[c], vs[c], Cs[c], Fs[c], ms[c], jps[c]);
        ((float4*)(out + OUT_F))[n] = make_float4(po.o00, po.o01, po.o10, po.o11);
        out[OUT_MAT + n] = (float)ms[c];
        out[OUT_JP + n] = po.jp_new;
        int t = pk[c] >> 16, r = pk[c] & 0xffff;
        int pos = lbase[t] + r;
        rec[2 * pos]     = make_float4(xs[c].x, xs[c].y, po.mom0, po.mom1);
        rec[2 * pos + 1] = make_float4(po.aff00, po.aff01, po.aff10, po.aff11);
    }
}

// ---- Pass 4: tiled P2G, fully coalesced record stream ----
__global__ __launch_bounds__(P2G_THREADS) void p2g_kernel(
    const float4* __restrict__ rec, const int* __restrict__ binBase,
    const int* __restrict__ binCount,
    float* __restrict__ gv, float* __restrict__ gm)
{
    __shared__ float s_v0[SUBN], s_v1[SUBN], s_m[SUBN];
    int tid = threadIdx.x;
    int tile = blockIdx.x >> 3;
    int sub  = blockIdx.x & (P2G_SUB - 1);
    for (int i = tid; i < SUBN; i += P2G_THREADS) {
        s_v0[i] = 0.f; s_v1[i] = 0.f; s_m[i] = 0.f;
    }
    __syncthreads();
    int start = binBase[tile];
    int cnt = binCount[tile];
    int t0 = (tile >> 3) << 4;
    int t1 = (tile & 7) << 4;
    const float DX = 1.0f / 128.0f;
    const float P_MASS = 1.52587890625e-05f;

    for (int p = sub * P2G_THREADS + tid; p < cnt; p += P2G_SUB * P2G_THREADS) {
        float4 r0 = rec[2 * (start + p)];
        float4 r1 = rec[2 * (start + p) + 1];
        float xg0 = r0.x * 128.0f, xg1 = r0.y * 128.0f;
        int b0 = (int)floorf(xg0 - 0.5f), b1 = (int)floorf(xg1 - 0.5f);
        float fx0 = xg0 - (float)b0, fx1 = xg1 - (float)b1;
        float wx[3], wy[3];
        quad_weights(fx0, wx);
        quad_weights(fx1, wy);
        int l0 = b0 - t0, l1 = b1 - t1;
        #pragma unroll
        for (int i = 0; i < 3; ++i) {
            float nx0 = (float)(b0 + i) * DX;
            #pragma unroll
            for (int j = 0; j < 3; ++j) {
                float wt = wx[i] * wy[j];
                float nx1 = (float)(b1 + j) * DX;
                int l = (l0 + i) * SUBW + (l1 + j);
                atomicAdd(&s_v0[l], wt * (r0.z + r1.x * nx0 + r1.y * nx1));
                atomicAdd(&s_v1[l], wt * (r0.w + r1.z * nx0 + r1.w * nx1));
                atomicAdd(&s_m[l], wt * P_MASS);
            }
        }
    }
    __syncthreads();
    for (int l = tid; l < SUBN; l += P2G_THREADS) {
        float m = s_m[l];
        if (m != 0.f) {
            int gi = t0 + l / SUBW, gj = t1 + l % SUBW;
            if (gi < NGRID && gj < NGRID) {
                int g = gi * NGRID + gj;
                unsafeAtomicAdd(&gv[2 * g], s_v0[l]);
                unsafeAtomicAdd(&gv[2 * g + 1], s_v1[l]);
                unsafeAtomicAdd(&gm[g], m);
            }
        }
    }
}

// ---- Pass 5: grid update ----
__global__ __launch_bounds__(256) void grid_kernel(
    float* __restrict__ gv, const float* __restrict__ gm)
{
    int idx = blockIdx.x * blockDim.x + threadIdx.x;
    if (idx >= NNODES) return;
    int i = idx >> 7, j = idx & 127;
    float m = gm[idx];
    float v0 = gv[2 * idx], v1 = gv[2 * idx + 1];
    if (m > 0.0f) {
        v0 /= m;
        v1 /= m;
        v1 -= 5e-3f;   // -DT*50
    }
    if (i < 3) v0 = fmaxf(v0, 0.0f);
    if (i >= NGRID - 2) v0 = fminf(v0, 0.0f);
    if (j < 3) v1 = fmaxf(v1, 0.0f);
    if (j >= NGRID - 2) v1 = fminf(v1, 0.0f);
    gv[2 * idx] = v0;
    gv[2 * idx + 1] = v1;
}

// ---- Pass 6: G2P (no physics; grid is L2-resident) ----
__global__ __launch_bounds__(256) void g2p_kernel(
    const float2* __restrict__ x, const float* __restrict__ gv,
    float* __restrict__ out)
{
    int n = blockIdx.x * blockDim.x + threadIdx.x;
    if (n >= NPART) return;
    const float DX = 1.0f / 128.0f;
    const float DT = 1e-4f;
    const float K4 = 65536.0f;

    float2 xx = x[n];
    float xg0 = xx.x * 128.0f, xg1 = xx.y * 128.0f;
    int b0 = (int)floorf(xg0 - 0.5f), b1 = (int)floorf(xg1 - 0.5f);
    float fx0 = xg0 - (float)b0, fx1 = xg1 - (float)b1;
    float wx[3], wy[3];
    quad_weights(fx0, wx);
    quad_weights(fx1, wy);

    float nv0 = 0.f, nv1 = 0.f;
    float nC00 = 0.f, nC01 = 0.f, nC10 = 0.f, nC11 = 0.f;
    #pragma unroll
    for (int i = 0; i < 3; ++i) {
        float node0 = (float)(b0 + i) * DX;
        #pragma unroll
        for (int j = 0; j < 3; ++j) {
            float wt = wx[i] * wy[j];
            int idx = (b0 + i) * NGRID + (b1 + j);
            float g0 = gv[2 * idx], g1 = gv[2 * idx + 1];
            float node1 = (float)(b1 + j) * DX;
            nv0 += wt * g0;
            nv1 += wt * g1;
            nC00 += wt * g0 * node0;
            nC01 += wt * g0 * node1;
            nC10 += wt * g1 * node0;
            nC11 += wt * g1 * node1;
        }
    }
    nC00 = (nC00 - nv0 * xx.x) * K4;
    nC01 = (nC01 - nv0 * xx.y) * K4;
    nC10 = (nC10 - nv1 * xx.x) * K4;
    nC11 = (nC11 - nv1 * xx.y) * K4;

    ((float2*)(out + OUT_X))[n] = make_float2(xx.x + DT * nv0, xx.y + DT * nv1);
    ((float2*)(out + OUT_V))[n] = make_float2(nv0, nv1);
    ((float4*)(out + OUT_C))[n] = make_float4(nC00, nC01, nC10, nC11);
}

extern "C" void kernel_launch(void* const* d_in, const int* in_sizes, int n_in,
                              void* d_out, int out_size, void* d_ws, size_t ws_size,
                              hipStream_t stream)
{
    const float2* x = (const float2*)d_in[0];
    const float2* v = (const float2*)d_in[1];
    const float4* C = (const float4*)d_in[2];
    const float4* F = (const float4*)d_in[3];
    const int* material = (const int*)d_in[4];
    const float* Jp = (const float*)d_in[5];
    float* out = (float*)d_out;

    // workspace: gv (2*NNODES f), gm (NNODES f), binCount/binBase/binCursor (64 ints each)
    float* gv = (float*)d_ws;
    float* gm = gv + 2 * NNODES;
    int* binCount = (int*)(gm + NNODES);
    int* binBase = binCount + NBINS;
    int* binCursor = binBase + NBINS;

    // packed records live in the not-yet-written x/v/C output region (32 MB)
    float4* rec = (float4*)out;

    // zero gv, gm, binCount in one contiguous memset
    hipMemsetAsync(d_ws, 0, (size_t)(3 * NNODES) * sizeof(float) + NBINS * sizeof(int), stream);

    hist_kernel<<<HIST_BLOCKS, 256, 0, stream>>>(x, binCount);
    base_kernel<<<1, 64, 0, stream>>>(binCount, binBase, binCursor);
    phys_scatter_kernel<<<PS_BLOCKS, 256, 0, stream>>>(x, v, C, F, material, Jp,
                                                       binCursor, out, rec);
    p2g_kernel<<<NBINS * P2G_SUB, P2G_THREADS, 0, stream>>>(rec, binBase, binCount, gv, gm);
    grid_kernel<<<NNODES / 256, 256, 0, stream>>>(gv, gm);
    g2p_kernel<<<(NPART + 255) / 256, 256, 0, stream>>>(x, gv, out);
}

// Round 4
// 386.098 us; speedup vs baseline: 1.0056x; 1.0056x over previous
//
#include <hip/hip_runtime.h>

#define NPART 1000000
#define NGRID 128
#define NNODES (NGRID * NGRID)
#define NBINS 64               // 8x8 tiles of 16x16 nodes
#define SUBW 18                // 16 + 2 halo (high side)
#define SUBN (SUBW * SUBW)     // 324
#define P2G_SUB 8              // sub-blocks per tile
#define P2G_THREADS 512
#define PS_CHUNK 4
#define PS_BLOCKS 977          // ceil(1e6 / (256*4))
#define HIST_BLOCKS 489        // ceil(1e6 / (256*8))

// Output flat offsets (floats), return order: x, v, C, F, material, Jp
#define OUT_X   0
#define OUT_V   2000000
#define OUT_C   4000000
#define OUT_F   8000000
#define OUT_MAT 12000000
#define OUT_JP  13000000

__device__ __forceinline__ void quad_weights(float fx, float w[3]) {
    w[0] = 0.5f * (1.5f - fx) * (1.5f - fx);
    w[1] = 0.75f - (fx - 1.0f) * (fx - 1.0f);
    w[2] = 0.5f * (fx - 0.5f) * (fx - 0.5f);
}

struct PhysOut {
    float o00, o01, o10, o11;      // projected F (output)
    float aff00, aff01, aff10, aff11;
    float mom0, mom1;
    float jp_new;
};

__device__ __forceinline__ PhysOut particle_phys(
    float2 xx, float2 vv, float4 Cm, float4 Fin, int mat, float jp)
{
    const float DT = 1e-4f;
    const float P_MASS = 1.52587890625e-05f;
    const float MU_0 = (float)(1000.0 / (2.0 * 1.2));
    const float LAMBDA_0 = (float)(200.0 / 0.72);
    const float SCALE = -1e-4f;   // -DT*P_VOL*4*INV_DX^2 == -DT exactly

    float F00 = Fin.x + DT * (Cm.x * Fin.x + Cm.y * Fin.z);
    float F01 = Fin.y + DT * (Cm.x * Fin.y + Cm.y * Fin.w);
    float F10 = Fin.z + DT * (Cm.z * Fin.x + Cm.w * Fin.z);
    float F11 = Fin.w + DT * (Cm.z * Fin.y + Cm.w * Fin.w);

    float h = (mat == 1) ? 0.3f : expf(10.0f * (1.0f - jp));
    float mu = (mat == 0) ? 0.0f : MU_0 * h;
    float lam = LAMBDA_0 * h;

    // closed-form 2x2 SVD
    float Es = 0.5f * (F00 + F11), Fs = 0.5f * (F00 - F11);
    float Gs = 0.5f * (F01 + F10), Hs = 0.5f * (F10 - F01);
    float Qs = sqrtf(Es * Es + Hs * Hs);
    float Rs = sqrtf(Fs * Fs + Gs * Gs);
    float s1 = Qs + Rs, s2 = Qs - Rs;
    float a_sum = atan2f(Gs, Fs);
    float a_dif = atan2f(Hs, Es);
    float ua = 0.5f * (a_sum + a_dif);
    float va = 0.5f * (a_sum - a_dif);
    float su, cu, sv, cv;
    sincosf(ua, &su, &cu);
    sincosf(va, &sv, &cv);

    float c1 = fminf(fmaxf(s1, 1.0f - 2.5e-2f), 1.0f + 4.5e-3f);
    float c2 = fminf(fmaxf(s2, 1.0f - 2.5e-2f), 1.0f + 4.5e-3f);
    float jp_new = jp;
    float sg1 = s1, sg2 = s2;
    if (mat == 2) {
        jp_new = jp * (s1 / c1) * (s2 / c2);
        sg1 = c1;
        sg2 = c2;
    }
    float J = sg1 * sg2;

    float R00 = cu * cv + su * sv;
    float R01 = cu * sv - su * cv;
    float R10 = su * cv - cu * sv;
    float R11 = su * sv + cu * cv;

    float o00, o01, o10, o11;
    if (mat == 0) {
        float sq = sqrtf(J);
        o00 = sq; o01 = 0.0f; o10 = 0.0f; o11 = sq;
    } else if (mat == 2) {
        o00 = sg1 * cu * cv + sg2 * su * sv;
        o01 = sg1 * cu * sv - sg2 * su * cv;
        o10 = sg1 * su * cv - sg2 * cu * sv;
        o11 = sg1 * su * sv + sg2 * cu * cv;
    } else {
        o00 = F00; o01 = F01; o10 = F10; o11 = F11;
    }

    float A00 = o00 - R00, A01 = o01 - R01, A10 = o10 - R10, A11 = o11 - R11;
    float S00 = A00 * o00 + A01 * o01;
    float S01 = A00 * o10 + A01 * o11;
    float S10 = A10 * o00 + A11 * o01;
    float S11 = A10 * o10 + A11 * o11;
    float ljj = lam * J * (J - 1.0f);

    PhysOut po;
    po.o00 = o00; po.o01 = o01; po.o10 = o10; po.o11 = o11;
    po.aff00 = SCALE * (2.0f * mu * S00 + ljj) + P_MASS * Cm.x;
    po.aff01 = SCALE * (2.0f * mu * S01)       + P_MASS * Cm.y;
    po.aff10 = SCALE * (2.0f * mu * S10)       + P_MASS * Cm.z;
    po.aff11 = SCALE * (2.0f * mu * S11 + ljj) + P_MASS * Cm.w;
    po.mom0 = P_MASS * vv.x - (po.aff00 * xx.x + po.aff01 * xx.y);
    po.mom1 = P_MASS * vv.y - (po.aff10 * xx.x + po.aff11 * xx.y);
    po.jp_new = jp_new;
    return po;
}

__device__ __forceinline__ int tile_of(float2 xx) {
    int b0 = (int)floorf(xx.x * 128.0f - 0.5f);
    int b1 = (int)floorf(xx.y * 128.0f - 0.5f);
    return ((b0 >> 4) << 3) | (b1 >> 4);
}

// ---- Pass 1: bin counts (LDS-reduced, 8 particles/thread) ----
__global__ __launch_bounds__(256) void hist_kernel(
    const float2* __restrict__ x, int* __restrict__ binCount)
{
    __shared__ int lh[NBINS];
    int tid = threadIdx.x;
    if (tid < NBINS) lh[tid] = 0;
    __syncthreads();
    int base = blockIdx.x * 2048;
    #pragma unroll
    for (int k = 0; k < 8; ++k) {
        int n = base + k * 256 + tid;
        if (n < NPART) atomicAdd(&lh[tile_of(x[n])], 1);
    }
    __syncthreads();
    if (tid < NBINS) {
        int c = lh[tid];
        if (c) atomicAdd(&binCount[tid], c);
    }
}

// ---- Pass 2: exclusive scan of 64 bin totals (one wave) ----
__global__ void base_kernel(const int* __restrict__ binCount,
                            int* __restrict__ binBase, int* __restrict__ binCursor)
{
    int lane = threadIdx.x;   // 64 threads
    int v = binCount[lane];
    int incl = v;
    for (int off = 1; off < 64; off <<= 1) {
        int t = __shfl_up(incl, off, 64);
        if (lane >= off) incl += t;
    }
    binBase[lane] = incl - v;
    binCursor[lane] = incl - v;
}

// ---- Pass 3: physics + packed-record scatter + F/mat/Jp outputs ----
__global__ __launch_bounds__(256) void phys_scatter_kernel(
    const float2* __restrict__ x, const float2* __restrict__ v,
    const float4* __restrict__ C, const float4* __restrict__ F,
    const int* __restrict__ material, const float* __restrict__ Jp,
    int* __restrict__ binCursor, float* __restrict__ out, float4* __restrict__ rec)
{
    __shared__ int lh[NBINS];
    __shared__ int lbase[NBINS];
    int tid = threadIdx.x;
    if (tid < NBINS) lh[tid] = 0;
    __syncthreads();
    int base = blockIdx.x * (256 * PS_CHUNK);

    float2 xs[PS_CHUNK], vs[PS_CHUNK];
    float4 Cs[PS_CHUNK], Fs[PS_CHUNK];
    float jps[PS_CHUNK];
    int ms[PS_CHUNK], pk[PS_CHUNK];

    #pragma unroll
    for (int c = 0; c < PS_CHUNK; ++c) {
        int n = base + c * 256 + tid;
        if (n < NPART) {
            xs[c] = x[n]; vs[c] = v[n]; Cs[c] = C[n]; Fs[c] = F[n];
            ms[c] = material[n]; jps[c] = Jp[n];
            int t = tile_of(xs[c]);
            int r = atomicAdd(&lh[t], 1);
            pk[c] = (t << 16) | r;
        } else pk[c] = -1;
    }
    __syncthreads();
    if (tid < NBINS) {
        int c = lh[tid];
        lbase[tid] = c ? atomicAdd(&binCursor[tid], c) : 0;
    }
    __syncthreads();

    #pragma unroll
    for (int c = 0; c < PS_CHUNK; ++c) {
        if (pk[c] < 0) continue;
        int n = base + c * 256 + tid;
        PhysOut po = particle_phys(xs[c], vs[c], Cs[c], Fs[c], ms[c], jps[c]);
        ((float4*)(out + OUT_F))[n] = make_float4(po.o00, po.o01, po.o10, po.o11);
        out[OUT_MAT + n] = (float)ms[c];
        out[OUT_JP + n] = po.jp_new;
        int t = pk[c] >> 16, r = pk[c] & 0xffff;
        int pos = lbase[t] + r;
        rec[2 * pos]     = make_float4(xs[c].x, xs[c].y, po.mom0, po.mom1);
        rec[2 * pos + 1] = make_float4(po.aff00, po.aff01, po.aff10, po.aff11);
    }
}

// ---- Pass 4: tiled P2G, coalesced record stream, native ds_add_f32 ----
__global__ __launch_bounds__(P2G_THREADS) void p2g_kernel(
    const float4* __restrict__ rec, const int* __restrict__ binBase,
    const int* __restrict__ binCount,
    float* __restrict__ gv, float* __restrict__ gm)
{
    __shared__ float s_v0[SUBN], s_v1[SUBN], s_m[SUBN];
    int tid = threadIdx.x;
    int tile = blockIdx.x >> 3;
    int sub  = blockIdx.x & (P2G_SUB - 1);
    for (int i = tid; i < SUBN; i += P2G_THREADS) {
        s_v0[i] = 0.f; s_v1[i] = 0.f; s_m[i] = 0.f;
    }
    __syncthreads();
    int start = binBase[tile];
    int cnt = binCount[tile];
    int t0 = (tile >> 3) << 4;
    int t1 = (tile & 7) << 4;
    const float DX = 1.0f / 128.0f;
    const float P_MASS = 1.52587890625e-05f;

    for (int p = sub * P2G_THREADS + tid; p < cnt; p += P2G_SUB * P2G_THREADS) {
        float4 r0 = rec[2 * (start + p)];
        float4 r1 = rec[2 * (start + p) + 1];
        float xg0 = r0.x * 128.0f, xg1 = r0.y * 128.0f;
        int b0 = (int)floorf(xg0 - 0.5f), b1 = (int)floorf(xg1 - 0.5f);
        float fx0 = xg0 - (float)b0, fx1 = xg1 - (float)b1;
        float wx[3], wy[3];
        quad_weights(fx0, wx);
        quad_weights(fx1, wy);
        int l0 = b0 - t0, l1 = b1 - t1;
        #pragma unroll
        for (int i = 0; i < 3; ++i) {
            float nx0 = (float)(b0 + i) * DX;
            #pragma unroll
            for (int j = 0; j < 3; ++j) {
                float wt = wx[i] * wy[j];
                float nx1 = (float)(b1 + j) * DX;
                int l = (l0 + i) * SUBW + (l1 + j);
                // native ds_add_f32, no CAS loop, no lgkmcnt round-trip
                unsafeAtomicAdd(&s_v0[l], wt * (r0.z + r1.x * nx0 + r1.y * nx1));
                unsafeAtomicAdd(&s_v1[l], wt * (r0.w + r1.z * nx0 + r1.w * nx1));
                unsafeAtomicAdd(&s_m[l], wt * P_MASS);
            }
        }
    }
    __syncthreads();
    for (int l = tid; l < SUBN; l += P2G_THREADS) {
        float m = s_m[l];
        if (m != 0.f) {
            int gi = t0 + l / SUBW, gj = t1 + l % SUBW;
            if (gi < NGRID && gj < NGRID) {
                int g = gi * NGRID + gj;
                unsafeAtomicAdd(&gv[2 * g], s_v0[l]);
                unsafeAtomicAdd(&gv[2 * g + 1], s_v1[l]);
                unsafeAtomicAdd(&gm[g], m);
            }
        }
    }
}

// ---- Pass 5: grid update ----
__global__ __launch_bounds__(256) void grid_kernel(
    float* __restrict__ gv, const float* __restrict__ gm)
{
    int idx = blockIdx.x * blockDim.x + threadIdx.x;
    if (idx >= NNODES) return;
    int i = idx >> 7, j = idx & 127;
    float m = gm[idx];
    float v0 = gv[2 * idx], v1 = gv[2 * idx + 1];
    if (m > 0.0f) {
        v0 /= m;
        v1 /= m;
        v1 -= 5e-3f;   // -DT*50
    }
    if (i < 3) v0 = fmaxf(v0, 0.0f);
    if (i >= NGRID - 2) v0 = fminf(v0, 0.0f);
    if (j < 3) v1 = fmaxf(v1, 0.0f);
    if (j >= NGRID - 2) v1 = fminf(v1, 0.0f);
    gv[2 * idx] = v0;
    gv[2 * idx + 1] = v1;
}

// ---- Pass 6: G2P (no physics; grid is L2-resident) ----
__global__ __launch_bounds__(256) void g2p_kernel(
    const float2* __restrict__ x, const float* __restrict__ gv,
    float* __restrict__ out)
{
    int n = blockIdx.x * blockDim.x + threadIdx.x;
    if (n >= NPART) return;
    const float DX = 1.0f / 128.0f;
    const float DT = 1e-4f;
    const float K4 = 65536.0f;

    float2 xx = x[n];
    float xg0 = xx.x * 128.0f, xg1 = xx.y * 128.0f;
    int b0 = (int)floorf(xg0 - 0.5f), b1 = (int)floorf(xg1 - 0.5f);
    float fx0 = xg0 - (float)b0, fx1 = xg1 - (float)b1;
    float wx[3], wy[3];
    quad_weights(fx0, wx);
    quad_weights(fx1, wy);

    float nv0 = 0.f, nv1 = 0.f;
    float nC00 = 0.f, nC01 = 0.f, nC10 = 0.f, nC11 = 0.f;
    #pragma unroll
    for (int i = 0; i < 3; ++i) {
        float node0 = (float)(b0 + i) * DX;
        #pragma unroll
        for (int j = 0; j < 3; ++j) {
            float wt = wx[i] * wy[j];
            int idx = (b0 + i) * NGRID + (b1 + j);
            float g0 = gv[2 * idx], g1 = gv[2 * idx + 1];
            float node1 = (float)(b1 + j) * DX;
            nv0 += wt * g0;
            nv1 += wt * g1;
            nC00 += wt * g0 * node0;
            nC01 += wt * g0 * node1;
            nC10 += wt * g1 * node0;
            nC11 += wt * g1 * node1;
        }
    }
    nC00 = (nC00 - nv0 * xx.x) * K4;
    nC01 = (nC01 - nv0 * xx.y) * K4;
    nC10 = (nC10 - nv1 * xx.x) * K4;
    nC11 = (nC11 - nv1 * xx.y) * K4;

    ((float2*)(out + OUT_X))[n] = make_float2(xx.x + DT * nv0, xx.y + DT * nv1);
    ((float2*)(out + OUT_V))[n] = make_float2(nv0, nv1);
    ((float4*)(out + OUT_C))[n] = make_float4(nC00, nC01, nC10, nC11);
}

extern "C" void kernel_launch(void* const* d_in, const int* in_sizes, int n_in,
                              void* d_out, int out_size, void* d_ws, size_t ws_size,
                              hipStream_t stream)
{
    const float2* x = (const float2*)d_in[0];
    const float2* v = (const float2*)d_in[1];
    const float4* C = (const float4*)d_in[2];
    const float4* F = (const float4*)d_in[3];
    const int* material = (const int*)d_in[4];
    const float* Jp = (const float*)d_in[5];
    float* out = (float*)d_out;

    // workspace: gv (2*NNODES f), gm (NNODES f), binCount/binBase/binCursor (64 ints each)
    float* gv = (float*)d_ws;
    float* gm = gv + 2 * NNODES;
    int* binCount = (int*)(gm + NNODES);
    int* binBase = binCount + NBINS;
    int* binCursor = binBase + NBINS;

    // packed records live in the not-yet-written x/v/C output region (32 MB)
    float4* rec = (float4*)out;

    // zero gv, gm, binCount in one contiguous memset
    hipMemsetAsync(d_ws, 0, (size_t)(3 * NNODES) * sizeof(float) + NBINS * sizeof(int), stream);

    hist_kernel<<<HIST_BLOCKS, 256, 0, stream>>>(x, binCount);
    base_kernel<<<1, 64, 0, stream>>>(binCount, binBase, binCursor);
    phys_scatter_kernel<<<PS_BLOCKS, 256, 0, stream>>>(x, v, C, F, material, Jp,
                                                       binCursor, out, rec);
    p2g_kernel<<<NBINS * P2G_SUB, P2G_THREADS, 0, stream>>>(rec, binBase, binCount, gv, gm);
    grid_kernel<<<NNODES / 256, 256, 0, stream>>>(gv, gm);
    g2p_kernel<<<(NPART + 255) / 256, 256, 0, stream>>>(x, gv, out);
}

// Round 5
// 190.907 us; speedup vs baseline: 2.0337x; 2.0224x over previous
//
#include <hip/hip_runtime.h>

#define NPART 1000000
#define NGRID 128
#define NNODES (NGRID * NGRID)
#define NBINS 64               // 8x8 tiles of 16x16 nodes
#define SUBW 18                // 16 + 2 halo (high side)
#define SUBN (SUBW * SUBW)     // 324
#define P2G_SUB 8              // sub-blocks per tile
#define P2G_THREADS 512
#define PS_CHUNK 4
#define PS_BLOCKS 977          // ceil(1e6 / (256*4))
#define HIST_BLOCKS 489        // ceil(1e6 / (256*8))

// fixed-point scale for LDS accumulation (int64, exact/associative)
#define FPSCALE 281474976710656.0f      // 2^48
#define FPINV   3.552713678800501e-15   // 2^-48 (double)

// Output flat offsets (floats), return order: x, v, C, F, material, Jp
#define OUT_X   0
#define OUT_V   2000000
#define OUT_C   4000000
#define OUT_F   8000000
#define OUT_MAT 12000000
#define OUT_JP  13000000

__device__ __forceinline__ void quad_weights(float fx, float w[3]) {
    w[0] = 0.5f * (1.5f - fx) * (1.5f - fx);
    w[1] = 0.75f - (fx - 1.0f) * (fx - 1.0f);
    w[2] = 0.5f * (fx - 0.5f) * (fx - 0.5f);
}

struct PhysOut {
    float o00, o01, o10, o11;      // projected F (output)
    float aff00, aff01, aff10, aff11;
    float mom0, mom1;
    float jp_new;
};

__device__ __forceinline__ PhysOut particle_phys(
    float2 xx, float2 vv, float4 Cm, float4 Fin, int mat, float jp)
{
    const float DT = 1e-4f;
    const float P_MASS = 1.52587890625e-05f;
    const float MU_0 = (float)(1000.0 / (2.0 * 1.2));
    const float LAMBDA_0 = (float)(200.0 / 0.72);
    const float SCALE = -1e-4f;   // -DT*P_VOL*4*INV_DX^2 == -DT exactly

    float F00 = Fin.x + DT * (Cm.x * Fin.x + Cm.y * Fin.z);
    float F01 = Fin.y + DT * (Cm.x * Fin.y + Cm.y * Fin.w);
    float F10 = Fin.z + DT * (Cm.z * Fin.x + Cm.w * Fin.z);
    float F11 = Fin.w + DT * (Cm.z * Fin.y + Cm.w * Fin.w);

    float h = (mat == 1) ? 0.3f : expf(10.0f * (1.0f - jp));
    float mu = (mat == 0) ? 0.0f : MU_0 * h;
    float lam = LAMBDA_0 * h;

    // closed-form 2x2 SVD
    float Es = 0.5f * (F00 + F11), Fs = 0.5f * (F00 - F11);
    float Gs = 0.5f * (F01 + F10), Hs = 0.5f * (F10 - F01);
    float Qs = sqrtf(Es * Es + Hs * Hs);
    float Rs = sqrtf(Fs * Fs + Gs * Gs);
    float s1 = Qs + Rs, s2 = Qs - Rs;
    float a_sum = atan2f(Gs, Fs);
    float a_dif = atan2f(Hs, Es);
    float ua = 0.5f * (a_sum + a_dif);
    float va = 0.5f * (a_sum - a_dif);
    float su, cu, sv, cv;
    sincosf(ua, &su, &cu);
    sincosf(va, &sv, &cv);

    float c1 = fminf(fmaxf(s1, 1.0f - 2.5e-2f), 1.0f + 4.5e-3f);
    float c2 = fminf(fmaxf(s2, 1.0f - 2.5e-2f), 1.0f + 4.5e-3f);
    float jp_new = jp;
    float sg1 = s1, sg2 = s2;
    if (mat == 2) {
        jp_new = jp * (s1 / c1) * (s2 / c2);
        sg1 = c1;
        sg2 = c2;
    }
    float J = sg1 * sg2;

    float R00 = cu * cv + su * sv;
    float R01 = cu * sv - su * cv;
    float R10 = su * cv - cu * sv;
    float R11 = su * sv + cu * cv;

    float o00, o01, o10, o11;
    if (mat == 0) {
        float sq = sqrtf(J);
        o00 = sq; o01 = 0.0f; o10 = 0.0f; o11 = sq;
    } else if (mat == 2) {
        o00 = sg1 * cu * cv + sg2 * su * sv;
        o01 = sg1 * cu * sv - sg2 * su * cv;
        o10 = sg1 * su * cv - sg2 * cu * sv;
        o11 = sg1 * su * sv + sg2 * cu * cv;
    } else {
        o00 = F00; o01 = F01; o10 = F10; o11 = F11;
    }

    float A00 = o00 - R00, A01 = o01 - R01, A10 = o10 - R10, A11 = o11 - R11;
    float S00 = A00 * o00 + A01 * o01;
    float S01 = A00 * o10 + A01 * o11;
    float S10 = A10 * o00 + A11 * o01;
    float S11 = A10 * o10 + A11 * o11;
    float ljj = lam * J * (J - 1.0f);

    PhysOut po;
    po.o00 = o00; po.o01 = o01; po.o10 = o10; po.o11 = o11;
    po.aff00 = SCALE * (2.0f * mu * S00 + ljj) + P_MASS * Cm.x;
    po.aff01 = SCALE * (2.0f * mu * S01)       + P_MASS * Cm.y;
    po.aff10 = SCALE * (2.0f * mu * S10)       + P_MASS * Cm.z;
    po.aff11 = SCALE * (2.0f * mu * S11 + ljj) + P_MASS * Cm.w;
    po.mom0 = P_MASS * vv.x - (po.aff00 * xx.x + po.aff01 * xx.y);
    po.mom1 = P_MASS * vv.y - (po.aff10 * xx.x + po.aff11 * xx.y);
    po.jp_new = jp_new;
    return po;
}

__device__ __forceinline__ int tile_of(float2 xx) {
    int b0 = (int)floorf(xx.x * 128.0f - 0.5f);
    int b1 = (int)floorf(xx.y * 128.0f - 0.5f);
    return ((b0 >> 4) << 3) | (b1 >> 4);
}

// ---- Pass 1: bin counts (LDS-reduced, 8 particles/thread) ----
__global__ __launch_bounds__(256) void hist_kernel(
    const float2* __restrict__ x, int* __restrict__ binCount)
{
    __shared__ int lh[NBINS];
    int tid = threadIdx.x;
    if (tid < NBINS) lh[tid] = 0;
    __syncthreads();
    int base = blockIdx.x * 2048;
    #pragma unroll
    for (int k = 0; k < 8; ++k) {
        int n = base + k * 256 + tid;
        if (n < NPART) atomicAdd(&lh[tile_of(x[n])], 1);
    }
    __syncthreads();
    if (tid < NBINS) {
        int c = lh[tid];
        if (c) atomicAdd(&binCount[tid], c);
    }
}

// ---- Pass 2: exclusive scan of 64 bin totals (one wave) ----
__global__ void base_kernel(const int* __restrict__ binCount,
                            int* __restrict__ binBase, int* __restrict__ binCursor)
{
    int lane = threadIdx.x;   // 64 threads
    int v = binCount[lane];
    int incl = v;
    for (int off = 1; off < 64; off <<= 1) {
        int t = __shfl_up(incl, off, 64);
        if (lane >= off) incl += t;
    }
    binBase[lane] = incl - v;
    binCursor[lane] = incl - v;
}

// ---- Pass 3: physics + packed-record scatter + F/mat/Jp outputs ----
__global__ __launch_bounds__(256) void phys_scatter_kernel(
    const float2* __restrict__ x, const float2* __restrict__ v,
    const float4* __restrict__ C, const float4* __restrict__ F,
    const int* __restrict__ material, const float* __restrict__ Jp,
    int* __restrict__ binCursor, float* __restrict__ out, float4* __restrict__ rec)
{
    __shared__ int lh[NBINS];
    __shared__ int lbase[NBINS];
    int tid = threadIdx.x;
    if (tid < NBINS) lh[tid] = 0;
    __syncthreads();
    int base = blockIdx.x * (256 * PS_CHUNK);

    float2 xs[PS_CHUNK], vs[PS_CHUNK];
    float4 Cs[PS_CHUNK], Fs[PS_CHUNK];
    float jps[PS_CHUNK];
    int ms[PS_CHUNK], pk[PS_CHUNK];

    #pragma unroll
    for (int c = 0; c < PS_CHUNK; ++c) {
        int n = base + c * 256 + tid;
        if (n < NPART) {
            xs[c] = x[n]; vs[c] = v[n]; Cs[c] = C[n]; Fs[c] = F[n];
            ms[c] = material[n]; jps[c] = Jp[n];
            int t = tile_of(xs[c]);
            int r = atomicAdd(&lh[t], 1);
            pk[c] = (t << 16) | r;
        } else pk[c] = -1;
    }
    __syncthreads();
    if (tid < NBINS) {
        int c = lh[tid];
        lbase[tid] = c ? atomicAdd(&binCursor[tid], c) : 0;
    }
    __syncthreads();

    #pragma unroll
    for (int c = 0; c < PS_CHUNK; ++c) {
        if (pk[c] < 0) continue;
        int n = base + c * 256 + tid;
        PhysOut po = particle_phys(xs[c], vs[c], Cs[c], Fs[c], ms[c], jps[c]);
        ((float4*)(out + OUT_F))[n] = make_float4(po.o00, po.o01, po.o10, po.o11);
        out[OUT_MAT + n] = (float)ms[c];
        out[OUT_JP + n] = po.jp_new;
        int t = pk[c] >> 16, r = pk[c] & 0xffff;
        int pos = lbase[t] + r;
        rec[2 * pos]     = make_float4(xs[c].x, xs[c].y, po.mom0, po.mom1);
        rec[2 * pos + 1] = make_float4(po.aff00, po.aff01, po.aff10, po.aff11);
    }
}

// ---- Pass 4: tiled P2G, int64 fixed-point LDS (native ds_add_u64, no CAS) ----
__global__ __launch_bounds__(P2G_THREADS) void p2g_kernel(
    const float4* __restrict__ rec, const int* __restrict__ binBase,
    const int* __restrict__ binCount,
    float* __restrict__ gv, float* __restrict__ gm)
{
    __shared__ unsigned long long s_v0[SUBN], s_v1[SUBN], s_m[SUBN];
    int tid = threadIdx.x;
    int tile = blockIdx.x >> 3;
    int sub  = blockIdx.x & (P2G_SUB - 1);
    for (int i = tid; i < SUBN; i += P2G_THREADS) {
        s_v0[i] = 0ull; s_v1[i] = 0ull; s_m[i] = 0ull;
    }
    __syncthreads();
    int start = binBase[tile];
    int cnt = binCount[tile];
    int t0 = (tile >> 3) << 4;
    int t1 = (tile & 7) << 4;
    const float DX = 1.0f / 128.0f;
    const float P_MASS = 1.52587890625e-05f;

    for (int p = sub * P2G_THREADS + tid; p < cnt; p += P2G_SUB * P2G_THREADS) {
        float4 r0 = rec[2 * (start + p)];
        float4 r1 = rec[2 * (start + p) + 1];
        float xg0 = r0.x * 128.0f, xg1 = r0.y * 128.0f;
        int b0 = (int)floorf(xg0 - 0.5f), b1 = (int)floorf(xg1 - 0.5f);
        float fx0 = xg0 - (float)b0, fx1 = xg1 - (float)b1;
        float wx[3], wy[3];
        quad_weights(fx0, wx);
        quad_weights(fx1, wy);
        int l0 = b0 - t0, l1 = b1 - t1;
        #pragma unroll
        for (int i = 0; i < 3; ++i) {
            float nx0 = (float)(b0 + i) * DX;
            #pragma unroll
            for (int j = 0; j < 3; ++j) {
                float wt = wx[i] * wy[j];
                float nx1 = (float)(b1 + j) * DX;
                int l = (l0 + i) * SUBW + (l1 + j);
                // integer LDS atomics: native ds_add_u64, fire-and-forget
                long long q0 = (long long)(wt * (r0.z + r1.x * nx0 + r1.y * nx1) * FPSCALE);
                long long q1 = (long long)(wt * (r0.w + r1.z * nx0 + r1.w * nx1) * FPSCALE);
                long long qm = (long long)(wt * P_MASS * FPSCALE);
                atomicAdd(&s_v0[l], (unsigned long long)q0);
                atomicAdd(&s_v1[l], (unsigned long long)q1);
                atomicAdd(&s_m[l], (unsigned long long)qm);
            }
        }
    }
    __syncthreads();
    for (int l = tid; l < SUBN; l += P2G_THREADS) {
        unsigned long long m = s_m[l];
        if (m != 0ull) {
            int gi = t0 + l / SUBW, gj = t1 + l % SUBW;
            if (gi < NGRID && gj < NGRID) {
                int g = gi * NGRID + gj;
                unsafeAtomicAdd(&gv[2 * g],     (float)((double)(long long)s_v0[l] * FPINV));
                unsafeAtomicAdd(&gv[2 * g + 1], (float)((double)(long long)s_v1[l] * FPINV));
                unsafeAtomicAdd(&gm[g],         (float)((double)(long long)m * FPINV));
            }
        }
    }
}

// ---- Pass 5: grid update ----
__global__ __launch_bounds__(256) void grid_kernel(
    float* __restrict__ gv, const float* __restrict__ gm)
{
    int idx = blockIdx.x * blockDim.x + threadIdx.x;
    if (idx >= NNODES) return;
    int i = idx >> 7, j = idx & 127;
    float m = gm[idx];
    float v0 = gv[2 * idx], v1 = gv[2 * idx + 1];
    if (m > 0.0f) {
        v0 /= m;
        v1 /= m;
        v1 -= 5e-3f;   // -DT*50
    }
    if (i < 3) v0 = fmaxf(v0, 0.0f);
    if (i >= NGRID - 2) v0 = fminf(v0, 0.0f);
    if (j < 3) v1 = fmaxf(v1, 0.0f);
    if (j >= NGRID - 2) v1 = fminf(v1, 0.0f);
    gv[2 * idx] = v0;
    gv[2 * idx + 1] = v1;
}

// ---- Pass 6: G2P (no physics; grid is L2-resident) ----
__global__ __launch_bounds__(256) void g2p_kernel(
    const float2* __restrict__ x, const float* __restrict__ gv,
    float* __restrict__ out)
{
    int n = blockIdx.x * blockDim.x + threadIdx.x;
    if (n >= NPART) return;
    const float DX = 1.0f / 128.0f;
    const float DT = 1e-4f;
    const float K4 = 65536.0f;

    float2 xx = x[n];
    float xg0 = xx.x * 128.0f, xg1 = xx.y * 128.0f;
    int b0 = (int)floorf(xg0 - 0.5f), b1 = (int)floorf(xg1 - 0.5f);
    float fx0 = xg0 - (float)b0, fx1 = xg1 - (float)b1;
    float wx[3], wy[3];
    quad_weights(fx0, wx);
    quad_weights(fx1, wy);

    float nv0 = 0.f, nv1 = 0.f;
    float nC00 = 0.f, nC01 = 0.f, nC10 = 0.f, nC11 = 0.f;
    #pragma unroll
    for (int i = 0; i < 3; ++i) {
        float node0 = (float)(b0 + i) * DX;
        #pragma unroll
        for (int j = 0; j < 3; ++j) {
            float wt = wx[i] * wy[j];
            int idx = (b0 + i) * NGRID + (b1 + j);
            float g0 = gv[2 * idx], g1 = gv[2 * idx + 1];
            float node1 = (float)(b1 + j) * DX;
            nv0 += wt * g0;
            nv1 += wt * g1;
            nC00 += wt * g0 * node0;
            nC01 += wt * g0 * node1;
            nC10 += wt * g1 * node0;
            nC11 += wt * g1 * node1;
        }
    }
    nC00 = (nC00 - nv0 * xx.x) * K4;
    nC01 = (nC01 - nv0 * xx.y) * K4;
    nC10 = (nC10 - nv1 * xx.x) * K4;
    nC11 = (nC11 - nv1 * xx.y) * K4;

    ((float2*)(out + OUT_X))[n] = make_float2(xx.x + DT * nv0, xx.y + DT * nv1);
    ((float2*)(out + OUT_V))[n] = make_float2(nv0, nv1);
    ((float4*)(out + OUT_C))[n] = make_float4(nC00, nC01, nC10, nC11);
}

extern "C" void kernel_launch(void* const* d_in, const int* in_sizes, int n_in,
                              void* d_out, int out_size, void* d_ws, size_t ws_size,
                              hipStream_t stream)
{
    const float2* x = (const float2*)d_in[0];
    const float2* v = (const float2*)d_in[1];
    const float4* C = (const float4*)d_in[2];
    const float4* F = (const float4*)d_in[3];
    const int* material = (const int*)d_in[4];
    const float* Jp = (const float*)d_in[5];
    float* out = (float*)d_out;

    // workspace: gv (2*NNODES f), gm (NNODES f), binCount/binBase/binCursor (64 ints each)
    float* gv = (float*)d_ws;
    float* gm = gv + 2 * NNODES;
    int* binCount = (int*)(gm + NNODES);
    int* binBase = binCount + NBINS;
    int* binCursor = binBase + NBINS;

    // packed records live in the not-yet-written x/v/C output region (32 MB)
    float4* rec = (float4*)out;

    // zero gv, gm, binCount in one contiguous memset
    hipMemsetAsync(d_ws, 0, (size_t)(3 * NNODES) * sizeof(float) + NBINS * sizeof(int), stream);

    hist_kernel<<<HIST_BLOCKS, 256, 0, stream>>>(x, binCount);
    base_kernel<<<1, 64, 0, stream>>>(binCount, binBase, binCursor);
    phys_scatter_kernel<<<PS_BLOCKS, 256, 0, stream>>>(x, v, C, F, material, Jp,
                                                       binCursor, out, rec);
    p2g_kernel<<<NBINS * P2G_SUB, P2G_THREADS, 0, stream>>>(rec, binBase, binCount, gv, gm);
    grid_kernel<<<NNODES / 256, 256, 0, stream>>>(gv, gm);
    g2p_kernel<<<(NPART + 255) / 256, 256, 0, stream>>>(x, gv, out);
}

// Round 6
// 175.151 us; speedup vs baseline: 2.2166x; 1.0900x over previous
//
#include <hip/hip_runtime.h>

#define NPART 1000000
#define NGRID 128
#define NNODES (NGRID * NGRID)
#define NBINS 64               // 8x8 tiles of 16x16 nodes
#define BINCAP 26624           // fixed slab capacity (max expected ~24.9K)
#define SUBW 18                // 16 + 2 halo (high side)
#define SUBN (SUBW * SUBW)     // 324
#define P2G_SUB 8              // sub-blocks per tile
#define P2G_THREADS 512
#define PS_CHUNK 4
#define PS_BLOCKS 977          // ceil(1e6 / (256*4))

// fixed-point scale for LDS accumulation (int64, exact/associative)
#define FPSCALE 281474976710656.0f      // 2^48
#define FPINV   3.552713678800501e-15   // 2^-48 (double)

// Output flat offsets (floats), return order: x, v, C, F, material, Jp
#define OUT_X   0
#define OUT_V   2000000
#define OUT_C   4000000
#define OUT_F   8000000
#define OUT_MAT 12000000
#define OUT_JP  13000000

__device__ __forceinline__ void quad_weights(float fx, float w[3]) {
    w[0] = 0.5f * (1.5f - fx) * (1.5f - fx);
    w[1] = 0.75f - (fx - 1.0f) * (fx - 1.0f);
    w[2] = 0.5f * (fx - 0.5f) * (fx - 0.5f);
}

struct PhysOut {
    float o00, o01, o10, o11;      // projected F (output)
    float aff00, aff01, aff10, aff11;
    float mom0, mom1;
    float jp_new;
};

// Trig-free closed-form 2x2 SVD consumer: all uses of U,V reduce to
// cos/sin of (u±v), which are direct ratios — no atan2/sincos needed.
__device__ __forceinline__ PhysOut particle_phys(
    float2 xx, float2 vv, float4 Cm, float4 Fin, int mat, float jp)
{
    const float DT = 1e-4f;
    const float P_MASS = 1.52587890625e-05f;
    const float MU_0 = (float)(1000.0 / (2.0 * 1.2));
    const float LAMBDA_0 = (float)(200.0 / 0.72);
    const float SCALE = -1e-4f;   // -DT*P_VOL*4*INV_DX^2 == -DT exactly

    float F00 = Fin.x + DT * (Cm.x * Fin.x + Cm.y * Fin.z);
    float F01 = Fin.y + DT * (Cm.x * Fin.y + Cm.y * Fin.w);
    float F10 = Fin.z + DT * (Cm.z * Fin.x + Cm.w * Fin.z);
    float F11 = Fin.w + DT * (Cm.z * Fin.y + Cm.w * Fin.w);

    float h = (mat == 1) ? 0.3f : expf(10.0f * (1.0f - jp));
    float mu = (mat == 0) ? 0.0f : MU_0 * h;
    float lam = LAMBDA_0 * h;

    float Es = 0.5f * (F00 + F11), Fs = 0.5f * (F00 - F11);
    float Gs = 0.5f * (F01 + F10), Hs = 0.5f * (F10 - F01);
    float q2 = Es * Es + Hs * Hs;
    float r2 = Fs * Fs + Gs * Gs;
    float Qs = sqrtf(q2);
    float Rs = sqrtf(r2);
    float s1 = Qs + Rs, s2 = Qs - Rs;
    // cos/sin of (u-v) and (u+v) as direct ratios (atan2(0,0)=0 convention)
    float cdif = 1.0f, sdif = 0.0f;
    if (q2 > 1e-30f) { float rq = 1.0f / Qs; cdif = Es * rq; sdif = Hs * rq; }
    float csum = 1.0f, ssum = 0.0f;
    if (r2 > 1e-30f) { float rr = 1.0f / Rs; csum = Fs * rr; ssum = Gs * rr; }
    float cucv = 0.5f * (cdif + csum);
    float susv = 0.5f * (cdif - csum);
    float cusv = 0.5f * (ssum - sdif);
    float sucv = 0.5f * (ssum + sdif);

    float c1 = fminf(fmaxf(s1, 1.0f - 2.5e-2f), 1.0f + 4.5e-3f);
    float c2 = fminf(fmaxf(s2, 1.0f - 2.5e-2f), 1.0f + 4.5e-3f);
    float jp_new = jp;
    float sg1 = s1, sg2 = s2;
    if (mat == 2) {
        jp_new = jp * (s1 / c1) * (s2 / c2);
        sg1 = c1;
        sg2 = c2;
    }
    float J = sg1 * sg2;

    // R = U V^T: rotation by (u-v)
    float R00 = cdif, R01 = -sdif;
    float R10 = sdif, R11 = cdif;

    float o00, o01, o10, o11;
    if (mat == 0) {
        float sq = sqrtf(J);
        o00 = sq; o01 = 0.0f; o10 = 0.0f; o11 = sq;
    } else if (mat == 2) {
        o00 = sg1 * cucv + sg2 * susv;
        o01 = sg1 * cusv - sg2 * sucv;
        o10 = sg1 * sucv - sg2 * cusv;
        o11 = sg1 * susv + sg2 * cucv;
    } else {
        o00 = F00; o01 = F01; o10 = F10; o11 = F11;
    }

    float A00 = o00 - R00, A01 = o01 - R01, A10 = o10 - R10, A11 = o11 - R11;
    float S00 = A00 * o00 + A01 * o01;
    float S01 = A00 * o10 + A01 * o11;
    float S10 = A10 * o00 + A11 * o01;
    float S11 = A10 * o10 + A11 * o11;
    float ljj = lam * J * (J - 1.0f);

    PhysOut po;
    po.o00 = o00; po.o01 = o01; po.o10 = o10; po.o11 = o11;
    po.aff00 = SCALE * (2.0f * mu * S00 + ljj) + P_MASS * Cm.x;
    po.aff01 = SCALE * (2.0f * mu * S01)       + P_MASS * Cm.y;
    po.aff10 = SCALE * (2.0f * mu * S10)       + P_MASS * Cm.z;
    po.aff11 = SCALE * (2.0f * mu * S11 + ljj) + P_MASS * Cm.w;
    po.mom0 = P_MASS * vv.x - (po.aff00 * xx.x + po.aff01 * xx.y);
    po.mom1 = P_MASS * vv.y - (po.aff10 * xx.x + po.aff11 * xx.y);
    po.jp_new = jp_new;
    return po;
}

__device__ __forceinline__ int tile_of(float2 xx) {
    int b0 = (int)floorf(xx.x * 128.0f - 0.5f);
    int b1 = (int)floorf(xx.y * 128.0f - 0.5f);
    return ((b0 >> 4) << 3) | (b1 >> 4);
}

// ---- Pass 1: physics + slab-record scatter + F/mat/Jp outputs ----
__global__ __launch_bounds__(256) void phys_scatter_kernel(
    const float2* __restrict__ x, const float2* __restrict__ v,
    const float4* __restrict__ C, const float4* __restrict__ F,
    const int* __restrict__ material, const float* __restrict__ Jp,
    int* __restrict__ binCursor, float* __restrict__ out, float4* __restrict__ rec)
{
    __shared__ int lh[NBINS];
    __shared__ int lbase[NBINS];
    int tid = threadIdx.x;
    if (tid < NBINS) lh[tid] = 0;
    __syncthreads();
    int base = blockIdx.x * (256 * PS_CHUNK);

    float2 xs[PS_CHUNK], vs[PS_CHUNK];
    float4 Cs[PS_CHUNK], Fs[PS_CHUNK];
    float jps[PS_CHUNK];
    int ms[PS_CHUNK], pk[PS_CHUNK];

    #pragma unroll
    for (int c = 0; c < PS_CHUNK; ++c) {
        int n = base + c * 256 + tid;
        if (n < NPART) {
            xs[c] = x[n]; vs[c] = v[n]; Cs[c] = C[n]; Fs[c] = F[n];
            ms[c] = material[n]; jps[c] = Jp[n];
            int t = tile_of(xs[c]);
            int r = atomicAdd(&lh[t], 1);
            pk[c] = (t << 16) | r;
        } else pk[c] = -1;
    }
    __syncthreads();
    if (tid < NBINS) {
        int c = lh[tid];
        lbase[tid] = c ? atomicAdd(&binCursor[tid], c) : 0;
    }
    __syncthreads();

    #pragma unroll
    for (int c = 0; c < PS_CHUNK; ++c) {
        if (pk[c] < 0) continue;
        int n = base + c * 256 + tid;
        PhysOut po = particle_phys(xs[c], vs[c], Cs[c], Fs[c], ms[c], jps[c]);
        ((float4*)(out + OUT_F))[n] = make_float4(po.o00, po.o01, po.o10, po.o11);
        out[OUT_MAT + n] = (float)ms[c];
        out[OUT_JP + n] = po.jp_new;
        int t = pk[c] >> 16, r = pk[c] & 0xffff;
        int pos = t * BINCAP + lbase[t] + r;
        rec[2 * pos]     = make_float4(xs[c].x, xs[c].y, po.mom0, po.mom1);
        rec[2 * pos + 1] = make_float4(po.aff00, po.aff01, po.aff10, po.aff11);
    }
}

// ---- Pass 2: tiled P2G, int64 fixed-point LDS (native ds_add_u64) ----
__global__ __launch_bounds__(P2G_THREADS) void p2g_kernel(
    const float4* __restrict__ rec, const int* __restrict__ binCursor,
    float* __restrict__ gv, float* __restrict__ gm)
{
    __shared__ unsigned long long s_v0[SUBN], s_v1[SUBN], s_m[SUBN];
    int tid = threadIdx.x;
    int tile = blockIdx.x >> 3;
    int sub  = blockIdx.x & (P2G_SUB - 1);
    for (int i = tid; i < SUBN; i += P2G_THREADS) {
        s_v0[i] = 0ull; s_v1[i] = 0ull; s_m[i] = 0ull;
    }
    __syncthreads();
    int start = tile * BINCAP;
    int cnt = binCursor[tile];
    int t0 = (tile >> 3) << 4;
    int t1 = (tile & 7) << 4;
    const float DX = 1.0f / 128.0f;
    const float MASS_FP = 4294967296.0f;   // P_MASS * 2^48 == 2^32 exactly

    for (int p = sub * P2G_THREADS + tid; p < cnt; p += P2G_SUB * P2G_THREADS) {
        float4 r0 = rec[2 * (start + p)];
        float4 r1 = rec[2 * (start + p) + 1];
        float xg0 = r0.x * 128.0f, xg1 = r0.y * 128.0f;
        int b0 = (int)floorf(xg0 - 0.5f), b1 = (int)floorf(xg1 - 0.5f);
        float fx0 = xg0 - (float)b0, fx1 = xg1 - (float)b1;
        float wx[3], wy[3];
        quad_weights(fx0, wx);
        quad_weights(fx1, wy);
        int l0 = b0 - t0, l1 = b1 - t1;
        #pragma unroll
        for (int i = 0; i < 3; ++i) {
            float nx0 = (float)(b0 + i) * DX;
            #pragma unroll
            for (int j = 0; j < 3; ++j) {
                float wt = wx[i] * wy[j];
                float nx1 = (float)(b1 + j) * DX;
                int l = (l0 + i) * SUBW + (l1 + j);
                long long q0 = (long long)(wt * (r0.z + r1.x * nx0 + r1.y * nx1) * FPSCALE);
                long long q1 = (long long)(wt * (r0.w + r1.z * nx0 + r1.w * nx1) * FPSCALE);
                long long qm = (long long)(wt * MASS_FP);
                atomicAdd(&s_v0[l], (unsigned long long)q0);
                atomicAdd(&s_v1[l], (unsigned long long)q1);
                atomicAdd(&s_m[l], (unsigned long long)qm);
            }
        }
    }
    __syncthreads();
    for (int l = tid; l < SUBN; l += P2G_THREADS) {
        unsigned long long m = s_m[l];
        if (m != 0ull) {
            int gi = t0 + l / SUBW, gj = t1 + l % SUBW;
            if (gi < NGRID && gj < NGRID) {
                int g = gi * NGRID + gj;
                unsafeAtomicAdd(&gv[2 * g],     (float)((double)(long long)s_v0[l] * FPINV));
                unsafeAtomicAdd(&gv[2 * g + 1], (float)((double)(long long)s_v1[l] * FPINV));
                unsafeAtomicAdd(&gm[g],         (float)((double)(long long)m * FPINV));
            }
        }
    }
}

// ---- Pass 3: grid update ----
__global__ __launch_bounds__(256) void grid_kernel(
    float* __restrict__ gv, const float* __restrict__ gm)
{
    int idx = blockIdx.x * blockDim.x + threadIdx.x;
    if (idx >= NNODES) return;
    int i = idx >> 7, j = idx & 127;
    float m = gm[idx];
    float v0 = gv[2 * idx], v1 = gv[2 * idx + 1];
    if (m > 0.0f) {
        v0 /= m;
        v1 /= m;
        v1 -= 5e-3f;   // -DT*50
    }
    if (i < 3) v0 = fmaxf(v0, 0.0f);
    if (i >= NGRID - 2) v0 = fminf(v0, 0.0f);
    if (j < 3) v1 = fmaxf(v1, 0.0f);
    if (j >= NGRID - 2) v1 = fminf(v1, 0.0f);
    gv[2 * idx] = v0;
    gv[2 * idx + 1] = v1;
}

// ---- Pass 4: G2P (grid is L1/L2-resident) ----
__global__ __launch_bounds__(256) void g2p_kernel(
    const float2* __restrict__ x, const float* __restrict__ gv,
    float* __restrict__ out)
{
    int n = blockIdx.x * blockDim.x + threadIdx.x;
    if (n >= NPART) return;
    const float DX = 1.0f / 128.0f;
    const float DT = 1e-4f;
    const float K4 = 65536.0f;

    float2 xx = x[n];
    float xg0 = xx.x * 128.0f, xg1 = xx.y * 128.0f;
    int b0 = (int)floorf(xg0 - 0.5f), b1 = (int)floorf(xg1 - 0.5f);
    float fx0 = xg0 - (float)b0, fx1 = xg1 - (float)b1;
    float wx[3], wy[3];
    quad_weights(fx0, wx);
    quad_weights(fx1, wy);

    float nv0 = 0.f, nv1 = 0.f;
    float nC00 = 0.f, nC01 = 0.f, nC10 = 0.f, nC11 = 0.f;
    #pragma unroll
    for (int i = 0; i < 3; ++i) {
        float node0 = (float)(b0 + i) * DX;
        #pragma unroll
        for (int j = 0; j < 3; ++j) {
            float wt = wx[i] * wy[j];
            int idx = (b0 + i) * NGRID + (b1 + j);
            float g0 = gv[2 * idx], g1 = gv[2 * idx + 1];
            float node1 = (float)(b1 + j) * DX;
            nv0 += wt * g0;
            nv1 += wt * g1;
            nC00 += wt * g0 * node0;
            nC01 += wt * g0 * node1;
            nC10 += wt * g1 * node0;
            nC11 += wt * g1 * node1;
        }
    }
    nC00 = (nC00 - nv0 * xx.x) * K4;
    nC01 = (nC01 - nv0 * xx.y) * K4;
    nC10 = (nC10 - nv1 * xx.x) * K4;
    nC11 = (nC11 - nv1 * xx.y) * K4;

    ((float2*)(out + OUT_X))[n] = make_float2(xx.x + DT * nv0, xx.y + DT * nv1);
    ((float2*)(out + OUT_V))[n] = make_float2(nv0, nv1);
    ((float4*)(out + OUT_C))[n] = make_float4(nC00, nC01, nC10, nC11);
}

extern "C" void kernel_launch(void* const* d_in, const int* in_sizes, int n_in,
                              void* d_out, int out_size, void* d_ws, size_t ws_size,
                              hipStream_t stream)
{
    const float2* x = (const float2*)d_in[0];
    const float2* v = (const float2*)d_in[1];
    const float4* C = (const float4*)d_in[2];
    const float4* F = (const float4*)d_in[3];
    const int* material = (const int*)d_in[4];
    const float* Jp = (const float*)d_in[5];
    float* out = (float*)d_out;

    // workspace: gv (2*NNODES f), gm (NNODES f), binCursor (64 int), rec slabs
    float* gv = (float*)d_ws;
    float* gm = gv + 2 * NNODES;
    int* binCursor = (int*)(gm + NNODES);
    float4* rec = (float4*)((char*)d_ws + (1 << 20));   // 1 MB offset, 54.5 MB slabs

    // zero gv, gm, binCursor in one contiguous memset
    hipMemsetAsync(d_ws, 0, (size_t)(3 * NNODES) * sizeof(float) + NBINS * sizeof(int), stream);

    phys_scatter_kernel<<<PS_BLOCKS, 256, 0, stream>>>(x, v, C, F, material, Jp,
                                                       binCursor, out, rec);
    p2g_kernel<<<NBINS * P2G_SUB, P2G_THREADS, 0, stream>>>(rec, binCursor, gv, gm);
    grid_kernel<<<NNODES / 256, 256, 0, stream>>>(gv, gm);
    g2p_kernel<<<(NPART + 255) / 256, 256, 0, stream>>>(x, gv, out);
}

// Round 7
// 173.886 us; speedup vs baseline: 2.2328x; 1.0073x over previous
//
#include <hip/hip_runtime.h>

#define NPART 1000000
#define NGRID 128
#define NNODES (NGRID * NGRID)
#define NBINS 64               // 8x8 tiles of 16x16 nodes
#define BINCAP 26624           // fixed slab capacity (max expected ~24.9K)
#define SUBW 18                // 16 + 2 halo (high side)
#define SUBN (SUBW * SUBW)     // 324
#define P2G_SUB 8              // sub-blocks per tile
#define P2G_THREADS 512
#define PS_CHUNK 4
#define PS_BLOCKS 977          // ceil(1e6 / (256*4))

// fixed-point scales for LDS accumulation (integer atomics, exact/associative)
#define FPSCALE 281474976710656.0f      // 2^48 (velocity, int64)
#define FPINV   3.552713678800501e-15   // 2^-48 (double)
#define WSCALE  16777216.0f             // 2^24 (weight sum, uint32)
#define WINV    5.9604644775390625e-8   // 2^-24

// Output flat offsets (floats), return order: x, v, C, F, material, Jp
#define OUT_X   0
#define OUT_V   2000000
#define OUT_C   4000000
#define OUT_F   8000000
#define OUT_MAT 12000000
#define OUT_JP  13000000

__device__ __forceinline__ void quad_weights(float fx, float w[3]) {
    w[0] = 0.5f * (1.5f - fx) * (1.5f - fx);
    w[1] = 0.75f - (fx - 1.0f) * (fx - 1.0f);
    w[2] = 0.5f * (fx - 0.5f) * (fx - 0.5f);
}

struct PhysOut {
    float o00, o01, o10, o11;      // projected F (output)
    float aff00, aff01, aff10, aff11;
    float mom0, mom1;
    float jp_new;
};

// Trig-free closed-form 2x2 SVD consumer.
__device__ __forceinline__ PhysOut particle_phys(
    float2 xx, float2 vv, float4 Cm, float4 Fin, int mat, float jp)
{
    const float DT = 1e-4f;
    const float P_MASS = 1.52587890625e-05f;
    const float MU_0 = (float)(1000.0 / (2.0 * 1.2));
    const float LAMBDA_0 = (float)(200.0 / 0.72);
    const float SCALE = -1e-4f;   // -DT*P_VOL*4*INV_DX^2 == -DT exactly

    float F00 = Fin.x + DT * (Cm.x * Fin.x + Cm.y * Fin.z);
    float F01 = Fin.y + DT * (Cm.x * Fin.y + Cm.y * Fin.w);
    float F10 = Fin.z + DT * (Cm.z * Fin.x + Cm.w * Fin.z);
    float F11 = Fin.w + DT * (Cm.z * Fin.y + Cm.w * Fin.w);

    float h = (mat == 1) ? 0.3f : expf(10.0f * (1.0f - jp));
    float mu = (mat == 0) ? 0.0f : MU_0 * h;
    float lam = LAMBDA_0 * h;

    float Es = 0.5f * (F00 + F11), Fs = 0.5f * (F00 - F11);
    float Gs = 0.5f * (F01 + F10), Hs = 0.5f * (F10 - F01);
    float q2 = Es * Es + Hs * Hs;
    float r2 = Fs * Fs + Gs * Gs;
    float Qs = sqrtf(q2);
    float Rs = sqrtf(r2);
    float s1 = Qs + Rs, s2 = Qs - Rs;
    float cdif = 1.0f, sdif = 0.0f;
    if (q2 > 1e-30f) { float rq = 1.0f / Qs; cdif = Es * rq; sdif = Hs * rq; }
    float csum = 1.0f, ssum = 0.0f;
    if (r2 > 1e-30f) { float rr = 1.0f / Rs; csum = Fs * rr; ssum = Gs * rr; }
    float cucv = 0.5f * (cdif + csum);
    float susv = 0.5f * (cdif - csum);
    float cusv = 0.5f * (ssum - sdif);
    float sucv = 0.5f * (ssum + sdif);

    float c1 = fminf(fmaxf(s1, 1.0f - 2.5e-2f), 1.0f + 4.5e-3f);
    float c2 = fminf(fmaxf(s2, 1.0f - 2.5e-2f), 1.0f + 4.5e-3f);
    float jp_new = jp;
    float sg1 = s1, sg2 = s2;
    if (mat == 2) {
        jp_new = jp * (s1 / c1) * (s2 / c2);
        sg1 = c1;
        sg2 = c2;
    }
    float J = sg1 * sg2;

    float R00 = cdif, R01 = -sdif;
    float R10 = sdif, R11 = cdif;

    float o00, o01, o10, o11;
    if (mat == 0) {
        float sq = sqrtf(J);
        o00 = sq; o01 = 0.0f; o10 = 0.0f; o11 = sq;
    } else if (mat == 2) {
        o00 = sg1 * cucv + sg2 * susv;
        o01 = sg1 * cusv - sg2 * sucv;
        o10 = sg1 * sucv - sg2 * cusv;
        o11 = sg1 * susv + sg2 * cucv;
    } else {
        o00 = F00; o01 = F01; o10 = F10; o11 = F11;
    }

    float A00 = o00 - R00, A01 = o01 - R01, A10 = o10 - R10, A11 = o11 - R11;
    float S00 = A00 * o00 + A01 * o01;
    float S01 = A00 * o10 + A01 * o11;
    float S10 = A10 * o00 + A11 * o01;
    float S11 = A10 * o10 + A11 * o11;
    float ljj = lam * J * (J - 1.0f);

    PhysOut po;
    po.o00 = o00; po.o01 = o01; po.o10 = o10; po.o11 = o11;
    po.aff00 = SCALE * (2.0f * mu * S00 + ljj) + P_MASS * Cm.x;
    po.aff01 = SCALE * (2.0f * mu * S01)       + P_MASS * Cm.y;
    po.aff10 = SCALE * (2.0f * mu * S10)       + P_MASS * Cm.z;
    po.aff11 = SCALE * (2.0f * mu * S11 + ljj) + P_MASS * Cm.w;
    po.mom0 = P_MASS * vv.x - (po.aff00 * xx.x + po.aff01 * xx.y);
    po.mom1 = P_MASS * vv.y - (po.aff10 * xx.x + po.aff11 * xx.y);
    po.jp_new = jp_new;
    return po;
}

__device__ __forceinline__ int tile_of(float2 xx) {
    int b0 = (int)floorf(xx.x * 128.0f - 0.5f);
    int b1 = (int)floorf(xx.y * 128.0f - 0.5f);
    return ((b0 >> 4) << 3) | (b1 >> 4);
}

// ---- Pass 1: physics + slab-record scatter + F/mat/Jp outputs ----
__global__ __launch_bounds__(256) void phys_scatter_kernel(
    const float2* __restrict__ x, const float2* __restrict__ v,
    const float4* __restrict__ C, const float4* __restrict__ F,
    const int* __restrict__ material, const float* __restrict__ Jp,
    int* __restrict__ binCursor, float* __restrict__ out, float4* __restrict__ rec)
{
    __shared__ int lh[NBINS];
    __shared__ int lbase[NBINS];
    int tid = threadIdx.x;
    if (tid < NBINS) lh[tid] = 0;
    __syncthreads();
    int base = blockIdx.x * (256 * PS_CHUNK);

    float2 xs[PS_CHUNK], vs[PS_CHUNK];
    float4 Cs[PS_CHUNK], Fs[PS_CHUNK];
    float jps[PS_CHUNK];
    int ms[PS_CHUNK], pk[PS_CHUNK];

    #pragma unroll
    for (int c = 0; c < PS_CHUNK; ++c) {
        int n = base + c * 256 + tid;
        if (n < NPART) {
            xs[c] = x[n]; vs[c] = v[n]; Cs[c] = C[n]; Fs[c] = F[n];
            ms[c] = material[n]; jps[c] = Jp[n];
            int t = tile_of(xs[c]);
            int r = atomicAdd(&lh[t], 1);
            pk[c] = (t << 16) | r;
        } else pk[c] = -1;
    }
    __syncthreads();
    if (tid < NBINS) {
        int c = lh[tid];
        lbase[tid] = c ? atomicAdd(&binCursor[tid], c) : 0;
    }
    __syncthreads();

    #pragma unroll
    for (int c = 0; c < PS_CHUNK; ++c) {
        if (pk[c] < 0) continue;
        int n = base + c * 256 + tid;
        PhysOut po = particle_phys(xs[c], vs[c], Cs[c], Fs[c], ms[c], jps[c]);
        ((float4*)(out + OUT_F))[n] = make_float4(po.o00, po.o01, po.o10, po.o11);
        out[OUT_MAT + n] = (float)ms[c];
        out[OUT_JP + n] = po.jp_new;
        int t = pk[c] >> 16, r = pk[c] & 0xffff;
        int pos = t * BINCAP + lbase[t] + r;
        rec[2 * pos]     = make_float4(xs[c].x, xs[c].y, po.mom0, po.mom1);
        rec[2 * pos + 1] = make_float4(po.aff00, po.aff01, po.aff10, po.aff11);
    }
}

// ---- Pass 2: tiled P2G; int LDS atomics; flush = plain stores to private slab ----
__global__ __launch_bounds__(P2G_THREADS) void p2g_kernel(
    const float4* __restrict__ rec, const int* __restrict__ binCursor,
    float* __restrict__ part)
{
    __shared__ unsigned long long s_v0[SUBN], s_v1[SUBN];
    __shared__ unsigned int s_m[SUBN];
    int tid = threadIdx.x;
    int tile = blockIdx.x >> 3;
    int sub  = blockIdx.x & (P2G_SUB - 1);
    for (int i = tid; i < SUBN; i += P2G_THREADS) {
        s_v0[i] = 0ull; s_v1[i] = 0ull; s_m[i] = 0u;
    }
    __syncthreads();
    int start = tile * BINCAP;
    int cnt = binCursor[tile];
    int t0 = (tile >> 3) << 4;
    int t1 = (tile & 7) << 4;
    const float DX = 1.0f / 128.0f;

    for (int p = sub * P2G_THREADS + tid; p < cnt; p += P2G_SUB * P2G_THREADS) {
        float4 r0 = rec[2 * (start + p)];
        float4 r1 = rec[2 * (start + p) + 1];
        float xg0 = r0.x * 128.0f, xg1 = r0.y * 128.0f;
        int b0 = (int)floorf(xg0 - 0.5f), b1 = (int)floorf(xg1 - 0.5f);
        float fx0 = xg0 - (float)b0, fx1 = xg1 - (float)b1;
        float wx[3], wy[3];
        quad_weights(fx0, wx);
        quad_weights(fx1, wy);
        int l0 = b0 - t0, l1 = b1 - t1;
        #pragma unroll
        for (int i = 0; i < 3; ++i) {
            float nx0 = (float)(b0 + i) * DX;
            #pragma unroll
            for (int j = 0; j < 3; ++j) {
                float wt = wx[i] * wy[j];
                float nx1 = (float)(b1 + j) * DX;
                int l = (l0 + i) * SUBW + (l1 + j);
                long long q0 = (long long)(wt * (r0.z + r1.x * nx0 + r1.y * nx1) * FPSCALE);
                long long q1 = (long long)(wt * (r0.w + r1.z * nx0 + r1.w * nx1) * FPSCALE);
                unsigned int qm = (unsigned int)(wt * WSCALE);
                atomicAdd(&s_v0[l], (unsigned long long)q0);
                atomicAdd(&s_v1[l], (unsigned long long)q1);
                atomicAdd(&s_m[l], qm);
            }
        }
    }
    __syncthreads();
    // private slab: no atomics, plain coalesced stores
    float* slab = part + (size_t)blockIdx.x * (3 * SUBN);
    for (int l = tid; l < SUBN; l += P2G_THREADS) {
        slab[l]            = (float)((double)(long long)s_v0[l] * FPINV);
        slab[SUBN + l]     = (float)((double)(long long)s_v1[l] * FPINV);
        slab[2 * SUBN + l] = (float)((double)s_m[l] * WINV);   // Σwt
    }
}

// ---- Pass 3: slab reduction + grid update ----
__global__ __launch_bounds__(256) void grid_kernel(
    const float* __restrict__ part, float2* __restrict__ gvn)
{
    int idx = blockIdx.x * blockDim.x + threadIdx.x;
    if (idx >= NNODES) return;
    const float P_MASS = 1.52587890625e-05f;
    int gi = idx >> 7, gj = idx & 127;
    int li = gi & 15, lj = gj & 15, ti = gi >> 4, tj = gj >> 4;

    int tis[2], l0s[2]; int ni = 1; tis[0] = ti; l0s[0] = li;
    if (li < 2 && ti > 0) { tis[1] = ti - 1; l0s[1] = li + 16; ni = 2; }
    int tjs[2], l1s[2]; int nj = 1; tjs[0] = tj; l1s[0] = lj;
    if (lj < 2 && tj > 0) { tjs[1] = tj - 1; l1s[1] = lj + 16; nj = 2; }

    float s0 = 0.f, s1 = 0.f, sw = 0.f;
    for (int a = 0; a < ni; ++a) {
        for (int b = 0; b < nj; ++b) {
            int tile2 = tis[a] * 8 + tjs[b];
            int l = l0s[a] * SUBW + l1s[b];
            const float* sb = part + (size_t)(tile2 * P2G_SUB) * (3 * SUBN) + l;
            #pragma unroll
            for (int sub = 0; sub < P2G_SUB; ++sub) {
                s0 += sb[0];
                s1 += sb[SUBN];
                sw += sb[2 * SUBN];
                sb += 3 * SUBN;
            }
        }
    }
    float m = sw * P_MASS;
    if (m > 0.f) {
        float rm = 1.0f / m;
        s0 *= rm;
        s1 *= rm;
        s1 -= 5e-3f;   // -DT*50
    }
    if (gi < 3) s0 = fmaxf(s0, 0.0f);
    if (gi >= NGRID - 2) s0 = fminf(s0, 0.0f);
    if (gj < 3) s1 = fmaxf(s1, 0.0f);
    if (gj >= NGRID - 2) s1 = fminf(s1, 0.0f);
    gvn[idx] = make_float2(s0, s1);
}

// ---- Pass 4: G2P (grid is L1/L2-resident) ----
__global__ __launch_bounds__(256) void g2p_kernel(
    const float2* __restrict__ x, const float2* __restrict__ gvn,
    float* __restrict__ out)
{
    int n = blockIdx.x * blockDim.x + threadIdx.x;
    if (n >= NPART) return;
    const float DX = 1.0f / 128.0f;
    const float DT = 1e-4f;
    const float K4 = 65536.0f;

    float2 xx = x[n];
    float xg0 = xx.x * 128.0f, xg1 = xx.y * 128.0f;
    int b0 = (int)floorf(xg0 - 0.5f), b1 = (int)floorf(xg1 - 0.5f);
    float fx0 = xg0 - (float)b0, fx1 = xg1 - (float)b1;
    float wx[3], wy[3];
    quad_weights(fx0, wx);
    quad_weights(fx1, wy);

    float nv0 = 0.f, nv1 = 0.f;
    float nC00 = 0.f, nC01 = 0.f, nC10 = 0.f, nC11 = 0.f;
    #pragma unroll
    for (int i = 0; i < 3; ++i) {
        float node0 = (float)(b0 + i) * DX;
        #pragma unroll
        for (int j = 0; j < 3; ++j) {
            float wt = wx[i] * wy[j];
            float2 g = gvn[(b0 + i) * NGRID + (b1 + j)];
            float node1 = (float)(b1 + j) * DX;
            nv0 += wt * g.x;
            nv1 += wt * g.y;
            nC00 += wt * g.x * node0;
            nC01 += wt * g.x * node1;
            nC10 += wt * g.y * node0;
            nC11 += wt * g.y * node1;
        }
    }
    nC00 = (nC00 - nv0 * xx.x) * K4;
    nC01 = (nC01 - nv0 * xx.y) * K4;
    nC10 = (nC10 - nv1 * xx.x) * K4;
    nC11 = (nC11 - nv1 * xx.y) * K4;

    ((float2*)(out + OUT_X))[n] = make_float2(xx.x + DT * nv0, xx.y + DT * nv1);
    ((float2*)(out + OUT_V))[n] = make_float2(nv0, nv1);
    ((float4*)(out + OUT_C))[n] = make_float4(nC00, nC01, nC10, nC11);
}

extern "C" void kernel_launch(void* const* d_in, const int* in_sizes, int n_in,
                              void* d_out, int out_size, void* d_ws, size_t ws_size,
                              hipStream_t stream)
{
    const float2* x = (const float2*)d_in[0];
    const float2* v = (const float2*)d_in[1];
    const float4* C = (const float4*)d_in[2];
    const float4* F = (const float4*)d_in[3];
    const int* material = (const int*)d_in[4];
    const float* Jp = (const float*)d_in[5];
    float* out = (float*)d_out;

    // workspace layout:
    //   [0,256B)      binCursor (64 ints)
    //   [4KB, ~2.5MB) part: 512 slabs x 3*SUBN floats
    //   [2.75MB, +128KB) gvn: normalized grid (float2 x 16384)
    //   [4MB, +54.5MB) rec slabs
    int* binCursor = (int*)d_ws;
    float* part = (float*)((char*)d_ws + 4096);
    float2* gvn = (float2*)((char*)d_ws + (11 << 18));          // 2.75 MB
    float4* rec = (float4*)((char*)d_ws + (4 << 20));           // 4 MB

    hipMemsetAsync(binCursor, 0, NBINS * sizeof(int), stream);

    phys_scatter_kernel<<<PS_BLOCKS, 256, 0, stream>>>(x, v, C, F, material, Jp,
                                                       binCursor, out, rec);
    p2g_kernel<<<NBINS * P2G_SUB, P2G_THREADS, 0, stream>>>(rec, binCursor, part);
    grid_kernel<<<NNODES / 256, 256, 0, stream>>>(part, gvn);
    g2p_kernel<<<(NPART + 255) / 256, 256, 0, stream>>>(x, gvn, out);
}